// Round 1
// baseline (284.591 us; speedup 1.0000x reference)
//
#include <hip/hip_runtime.h>
#include <cstdint>

typedef unsigned long long u64;

#define THRESH 0.5f
#define SIGMA 2.0f
#define TP 16        // pair-tile dimension (16x16 pairs per block)
#define CHUNK 128    // uint64 words per LDS chunk per mask
#define CSTRIDE 130  // padded LDS row stride (breaks 16-way bank conflict -> 2-way, free)

// ---------------------------------------------------------------------------
// K1: one block per mask. Reads mask_preds once (HBM floor ~131MB):
//   - bit-packs the binarized mask via 64-lane __ballot (4 words/wave/iter)
//   - accumulates pixel count and soft-score sum (fp64 for accuracy)
//   - writes scores[i] = cate_scores[i] * softsum / max(count,1), sums[i]
// Bit order within packed words is an arbitrary-but-fixed pixel permutation;
// popcount(AND) is permutation-invariant so intersection counts are exact.
// ---------------------------------------------------------------------------
__global__ __launch_bounds__(256) void k_pack_score(
    const float* __restrict__ preds, const float* __restrict__ cate,
    u64* __restrict__ packed, float* __restrict__ scores, float* __restrict__ sums,
    int HW)
{
    const int i = blockIdx.x;
    const float* src = preds + (size_t)i * HW;
    u64* dst = packed + (size_t)i * (HW >> 6);
    const int tid = threadIdx.x;
    const int wave = tid >> 6, lane = tid & 63;
    double ssum = 0.0;
    int cnt = 0;
    const int iters = HW >> 10;  // 1024 pixels per block iteration (4 waves * 64 lanes * 4)
    for (int k = 0; k < iters; ++k) {
        const int p = (k << 10) + (wave << 8) + (lane << 2);
        const float4 v = *reinterpret_cast<const float4*>(src + p);
        const bool b0 = v.x > THRESH, b1 = v.y > THRESH, b2 = v.z > THRESH, b3 = v.w > THRESH;
        const u64 m0 = __ballot(b0);
        const u64 m1 = __ballot(b1);
        const u64 m2 = __ballot(b2);
        const u64 m3 = __ballot(b3);
        if (lane < 4) {
            const u64 m = (lane == 0) ? m0 : (lane == 1) ? m1 : (lane == 2) ? m2 : m3;
            dst[(k << 4) + (wave << 2) + lane] = m;
        }
        cnt += (int)b0 + (int)b1 + (int)b2 + (int)b3;
        ssum += (b0 ? (double)v.x : 0.0) + (b1 ? (double)v.y : 0.0)
              + (b2 ? (double)v.z : 0.0) + (b3 ? (double)v.w : 0.0);
    }
    for (int off = 32; off > 0; off >>= 1) {
        ssum += __shfl_down(ssum, off);
        cnt  += __shfl_down(cnt, off);
    }
    __shared__ double ls[4];
    __shared__ int lc[4];
    if (lane == 0) { ls[wave] = ssum; lc[wave] = cnt; }
    __syncthreads();
    if (tid == 0) {
        const double S = ls[0] + ls[1] + ls[2] + ls[3];
        const int C = lc[0] + lc[1] + lc[2] + lc[3];
        const float seg = (float)(S / (double)(C > 1 ? C : 1));
        scores[i] = cate[i] * seg;
        sums[i] = (float)C;
    }
}

// ---------------------------------------------------------------------------
// K2: rank sort (descending score, stable ties by original index) — O(N^2),
// 250k comparisons total, trivial. rank is a permutation, so every sorted
// slot gets written exactly once.
// ---------------------------------------------------------------------------
__global__ void k_sort(const float* __restrict__ scores, const float* __restrict__ sums,
                       const int* __restrict__ labels,
                       float* __restrict__ sScore, float* __restrict__ sSum,
                       int* __restrict__ sLabel, int* __restrict__ order, int N)
{
    const int i = blockIdx.x * blockDim.x + threadIdx.x;
    if (i >= N) return;
    const float si = scores[i];
    int r = 0;
    for (int j = 0; j < N; ++j) {
        const float sj = scores[j];
        r += (sj > si) || (sj == si && j < i);
    }
    order[r] = i;
    sScore[r] = si;
    sSum[r] = sums[i];
    sLabel[r] = labels[i];
}

// ---------------------------------------------------------------------------
// K3: pairwise IoU, upper triangle only. Each block = 16x16 pair tile; the
// 32 needed masks are staged through LDS in 128-word chunks (32.5 KB LDS).
// Lane (a,b) accumulates popcount(mask_i[a] & mask_j[b]). CSTRIDE=130 makes
// the 16-way same-word broadcast reads land in distinct bank groups.
// D[i*N+j] = (labels match) ? inter/max(union,1) : 0, for i<j only —
// lower triangle is never read downstream, so poison there is harmless.
// ---------------------------------------------------------------------------
__global__ __launch_bounds__(256) void k_iou(
    const u64* __restrict__ packed, const int* __restrict__ order,
    const float* __restrict__ sSum, const int* __restrict__ sLabel,
    float* __restrict__ D, int N, int WORDS, int NT)
{
    __shared__ u64 sm[2 * TP][CSTRIDE];
    // decode upper-triangular tile index
    int b = blockIdx.x;
    int ti = 0, rowlen = NT;
    while (b >= rowlen) { b -= rowlen; ++ti; --rowlen; }
    const int tj = ti + b;

    const int tid = threadIdx.x;
    const int a = tid >> 4, bb = tid & 15;
    const int gi = ti * TP + a, gj = tj * TP + bb;

    unsigned inter = 0;
    const int nchunk = WORDS / CHUNK;
    for (int c = 0; c < nchunk; ++c) {
        const int base = c * CHUNK;
        for (int idx = tid; idx < 2 * TP * (CHUNK / 2); idx += 256) {
            const int ml = idx >> 6;            // CHUNK/2 == 64 ulong2 per mask row
            const int w = (idx & 63) << 1;
            const int g = (ml < TP) ? (ti * TP + ml) : (tj * TP + (ml - TP));
            u64 x0 = 0, x1 = 0;
            if (g < N) {
                const u64* p = packed + (size_t)order[g] * WORDS + base + w;
                x0 = p[0];
                x1 = p[1];
            }
            sm[ml][w] = x0;
            sm[ml][w + 1] = x1;
        }
        __syncthreads();
        const u64* pi = sm[a];
        const u64* pj = sm[TP + bb];
        #pragma unroll 8
        for (int w = 0; w < CHUNK; w += 2) {
            const u64 xi0 = pi[w], xi1 = pi[w + 1];
            const u64 xj0 = pj[w], xj1 = pj[w + 1];
            inter += (unsigned)__popcll(xi0 & xj0) + (unsigned)__popcll(xi1 & xj1);
        }
        __syncthreads();
    }
    if (gj < N && gi < gj) {
        const float fi = (float)inter;
        const float un = sSum[gi] + sSum[gj] - fi;   // exact: integers < 2^18
        const float iou = fi / fmaxf(un, 1.0f);
        D[(size_t)gi * N + gj] = (sLabel[gi] == sLabel[gj]) ? iou : 0.0f;
    }
}

// ---------------------------------------------------------------------------
// K4: comp[c] = max_{k<c} D[k][c]  (column max over the written upper tri;
// the implicit zeros of the full reference column are covered by init 0).
// ---------------------------------------------------------------------------
__global__ __launch_bounds__(256) void k_comp(const float* __restrict__ D,
                                              float* __restrict__ comp, int N)
{
    const int c = blockIdx.x;
    const int tid = threadIdx.x;
    float m = 0.0f;
    for (int k = tid; k < c; k += 256) m = fmaxf(m, D[(size_t)k * N + c]);
    for (int off = 32; off > 0; off >>= 1) m = fmaxf(m, __shfl_down(m, off));
    __shared__ float lm[4];
    const int wave = tid >> 6, lane = tid & 63;
    if (lane == 0) lm[wave] = m;
    __syncthreads();
    if (tid == 0) comp[c] = fmaxf(fmaxf(lm[0], lm[1]), fmaxf(lm[2], lm[3]));
}

// ---------------------------------------------------------------------------
// K5: coeff[j] = min_i exp(-sigma*(d^2 - comp[i]^2)) = exp(-sigma * m[j]),
// m[j] = max_i (d_ij^2 - comp[i]^2), d_ij = (i<j) ? D[i][j] : 0.
// out[j] = sortedScore[j] * coeff[j].
// ---------------------------------------------------------------------------
__global__ __launch_bounds__(256) void k_final(const float* __restrict__ D,
    const float* __restrict__ comp, const float* __restrict__ sScore,
    float* __restrict__ out, int N)
{
    const int j = blockIdx.x;
    const int tid = threadIdx.x;
    float m = -3.0e38f;
    for (int i = tid; i < N; i += 256) {
        const float ci = comp[i];
        const float d = (i < j) ? D[(size_t)i * N + j] : 0.0f;
        m = fmaxf(m, d * d - ci * ci);
    }
    for (int off = 32; off > 0; off >>= 1) m = fmaxf(m, __shfl_down(m, off));
    __shared__ float lm[4];
    const int wave = tid >> 6, lane = tid & 63;
    if (lane == 0) lm[wave] = m;
    __syncthreads();
    if (tid == 0) {
        const float mm = fmaxf(fmaxf(lm[0], lm[1]), fmaxf(lm[2], lm[3]));
        out[j] = sScore[j] * expf(-SIGMA * mm);
    }
}

extern "C" void kernel_launch(void* const* d_in, const int* in_sizes, int n_in,
                              void* d_out, int out_size, void* d_ws, size_t ws_size,
                              hipStream_t stream)
{
    const float* preds  = (const float*)d_in[0];
    const float* cate   = (const float*)d_in[1];
    const int*   labels = (const int*)d_in[2];
    float* out = (float*)d_out;

    const int N = in_sizes[1];
    const int HW = in_sizes[0] / N;
    const int WORDS = HW >> 6;

    char* ws = (char*)d_ws;
    size_t off = 0;
    auto take = [&](size_t bytes) -> void* {
        void* p = ws + off;
        off = (off + bytes + 255) & ~(size_t)255;
        return p;
    };
    u64*   packed = (u64*)  take((size_t)N * WORDS * sizeof(u64));   // ~4.1 MB
    float* scores = (float*)take((size_t)N * sizeof(float));
    float* sums   = (float*)take((size_t)N * sizeof(float));
    float* sScore = (float*)take((size_t)N * sizeof(float));
    float* sSum   = (float*)take((size_t)N * sizeof(float));
    int*   sLabel = (int*)  take((size_t)N * sizeof(int));
    int*   order  = (int*)  take((size_t)N * sizeof(int));
    float* comp   = (float*)take((size_t)N * sizeof(float));
    float* D      = (float*)take((size_t)N * N * sizeof(float));     // ~1.0 MB
    (void)ws_size; (void)n_in; (void)out_size;

    k_pack_score<<<N, 256, 0, stream>>>(preds, cate, packed, scores, sums, HW);

    k_sort<<<(N + 511) / 512, 512, 0, stream>>>(scores, sums, labels,
                                                sScore, sSum, sLabel, order, N);

    const int NT = (N + TP - 1) / TP;
    k_iou<<<NT * (NT + 1) / 2, 256, 0, stream>>>(packed, order, sSum, sLabel,
                                                 D, N, WORDS, NT);

    k_comp<<<N, 256, 0, stream>>>(D, comp, N);

    k_final<<<N, 256, 0, stream>>>(D, comp, sScore, out, N);
}

// Round 2
// 278.179 us; speedup vs baseline: 1.0230x; 1.0230x over previous
//
#include <hip/hip_runtime.h>
#include <cstdint>

typedef unsigned long long u64;

#define THRESH 0.5f
#define SIGMA 2.0f

#define TPB 64      // pair-tile dimension (64x64 pairs per block, 4x4 per thread)
#define NSPLIT 8    // K-dimension splits per tile
#define CH 64       // u64 words staged per chunk per mask
#define CST 66      // padded LDS row stride (u64): row quad-stride 33 mod 32 = 1 -> <=2-way, free

// ---------------------------------------------------------------------------
// K1: 4 blocks per mask (occupancy: 2000 blocks vs 500). Each block packs its
// quarter of the binarized mask via 64-lane __ballot and accumulates partial
// pixel count + fp64 soft-score sum. Partials finalized in k_sort.
// Bit order is an arbitrary fixed pixel permutation, identical for all masks,
// so popcount(AND) intersections are exact.
// ---------------------------------------------------------------------------
__global__ __launch_bounds__(256) void k_pack_score(
    const float* __restrict__ preds, u64* __restrict__ packed,
    double* __restrict__ pssum, int* __restrict__ pcnt, int HW)
{
    const int b = blockIdx.x;
    const int i = b >> 2, sub = b & 3;
    const int seg = HW >> 2;                       // pixels per sub-block
    const float* src = preds + (size_t)i * HW + (size_t)sub * seg;
    u64* dst = packed + (size_t)i * (HW >> 6) + (size_t)sub * (seg >> 6);
    const int tid = threadIdx.x;
    const int wave = tid >> 6, lane = tid & 63;
    double ssum = 0.0;
    int cnt = 0;
    const int iters = seg >> 10;                   // 1024 px per block-iter
    for (int k = 0; k < iters; ++k) {
        const int p = (k << 10) + (wave << 8) + (lane << 2);
        const float4 v = *reinterpret_cast<const float4*>(src + p);
        const bool b0 = v.x > THRESH, b1 = v.y > THRESH, b2 = v.z > THRESH, b3 = v.w > THRESH;
        const u64 m0 = __ballot(b0);
        const u64 m1 = __ballot(b1);
        const u64 m2 = __ballot(b2);
        const u64 m3 = __ballot(b3);
        if (lane < 4) {
            const u64 m = (lane == 0) ? m0 : (lane == 1) ? m1 : (lane == 2) ? m2 : m3;
            dst[(k << 4) + (wave << 2) + lane] = m;
        }
        cnt += (int)b0 + (int)b1 + (int)b2 + (int)b3;
        ssum += (b0 ? (double)v.x : 0.0) + (b1 ? (double)v.y : 0.0)
              + (b2 ? (double)v.z : 0.0) + (b3 ? (double)v.w : 0.0);
    }
    for (int off = 32; off > 0; off >>= 1) {
        ssum += __shfl_down(ssum, off);
        cnt  += __shfl_down(cnt, off);
    }
    __shared__ double ls[4];
    __shared__ int lc[4];
    if (lane == 0) { ls[wave] = ssum; lc[wave] = cnt; }
    __syncthreads();
    if (tid == 0) {
        pssum[b] = ls[0] + ls[1] + ls[2] + ls[3];
        pcnt[b]  = lc[0] + lc[1] + lc[2] + lc[3];
    }
}

// ---------------------------------------------------------------------------
// K2: single block. Finalize scores from sub-block partials, then O(N^2) rank
// sort (descending, stable ties by original index — matches jnp.argsort(-s)).
// ---------------------------------------------------------------------------
__global__ __launch_bounds__(512) void k_sort(
    const double* __restrict__ pssum, const int* __restrict__ pcnt,
    const float* __restrict__ cate, const int* __restrict__ labels,
    float* __restrict__ sScore, float* __restrict__ sSum,
    int* __restrict__ sLabel, int* __restrict__ order, int N)
{
    __shared__ float sc[512];
    const int i = threadIdx.x;
    float si = 0.f, su = 0.f;
    if (i < N) {
        const double S = pssum[4*i] + pssum[4*i+1] + pssum[4*i+2] + pssum[4*i+3];
        const int C = pcnt[4*i] + pcnt[4*i+1] + pcnt[4*i+2] + pcnt[4*i+3];
        si = cate[i] * (float)(S / (double)(C > 1 ? C : 1));
        su = (float)C;
        sc[i] = si;
    }
    __syncthreads();
    if (i < N) {
        int r = 0;
        for (int j = 0; j < N; ++j) {
            const float sj = sc[j];
            r += (sj > si) || (sj == si && j < i);
        }
        order[r] = i;
        sScore[r] = si;
        sSum[r] = su;
        sLabel[r] = labels[i];
    }
}

// ---------------------------------------------------------------------------
// K3: pairwise intersections. Grid (NTRI, NSPLIT): upper-tri 64x64 tiles x
// K-splits. 256 threads as 16x16, each computing a 4x4 pair sub-tile:
// 8 ds_read_b128 feed 16 pair-updates (4x fewer LDS instrs than 1 pair/thr).
// LDS: 128 rows x 66 u64 = 66 KB -> 2 blocks/CU. Partial counts combined via
// atomicAdd into zero-initialized interBuf (uint, exact).
// ---------------------------------------------------------------------------
__global__ __launch_bounds__(256) void k_inter(
    const u64* __restrict__ packed, const int* __restrict__ order,
    unsigned* __restrict__ interBuf, int N, int WORDS, int NT)
{
    __shared__ u64 sm[2 * TPB][CST];
    int b = blockIdx.x;
    int ti = 0, rowlen = NT;
    while (b >= rowlen) { b -= rowlen; ++ti; --rowlen; }
    const int tj = ti + b;
    const int kwords = WORDS / NSPLIT;
    const int kbase = blockIdx.y * kwords;

    const int tid = threadIdx.x;
    const int a = tid >> 4, bb = tid & 15;

    unsigned acc[4][4] = {};
    for (int c = 0; c < kwords / CH; ++c) {
        const int base = kbase + c * CH;
        // stage 128 mask-rows x CH words (32 ulong2 per row, 16 per thread)
        for (int idx = tid; idx < 2 * TPB * (CH / 2); idx += 256) {
            const int ml = idx >> 5;
            const int w = (idx & 31) << 1;
            const int g = (ml < TPB) ? (ti * TPB + ml) : (tj * TPB + (ml - TPB));
            u64 x0 = 0, x1 = 0;
            if (g < N) {
                const u64* p = packed + (size_t)order[g] * WORDS + base + w;
                x0 = p[0];
                x1 = p[1];
            }
            sm[ml][w] = x0;
            sm[ml][w + 1] = x1;
        }
        __syncthreads();
        #pragma unroll 2
        for (int w = 0; w < CH; w += 2) {
            u64 pi0[4], pi1[4], pj0[4], pj1[4];
            #pragma unroll
            for (int t = 0; t < 4; ++t) { pi0[t] = sm[4*a + t][w]; pi1[t] = sm[4*a + t][w + 1]; }
            #pragma unroll
            for (int s = 0; s < 4; ++s) { pj0[s] = sm[TPB + 4*bb + s][w]; pj1[s] = sm[TPB + 4*bb + s][w + 1]; }
            #pragma unroll
            for (int t = 0; t < 4; ++t)
                #pragma unroll
                for (int s = 0; s < 4; ++s)
                    acc[t][s] += (unsigned)__popcll(pi0[t] & pj0[s])
                               + (unsigned)__popcll(pi1[t] & pj1[s]);
        }
        __syncthreads();
    }
    #pragma unroll
    for (int t = 0; t < 4; ++t)
        #pragma unroll
        for (int s = 0; s < 4; ++s) {
            const int gi = ti * TPB + 4*a + t;
            const int gj = tj * TPB + 4*bb + s;
            if (gj < N && gi < gj) atomicAdd(&interBuf[(size_t)gi * N + gj], acc[t][s]);
        }
}

// ---------------------------------------------------------------------------
// K4: comp[c] = max_{k<c, label match} iou(k,c), iou recomputed from exact
// integer intersections (identical values to storing the float matrix).
// ---------------------------------------------------------------------------
__global__ __launch_bounds__(256) void k_comp(
    const unsigned* __restrict__ interBuf, const float* __restrict__ sSum,
    const int* __restrict__ sLabel, float* __restrict__ comp, int N)
{
    const int c = blockIdx.x;
    const int tid = threadIdx.x;
    const float suc = sSum[c];
    const int lc_ = sLabel[c];
    float m = 0.0f;
    for (int k = tid; k < c; k += 256) {
        if (sLabel[k] == lc_) {
            const float inter = (float)interBuf[(size_t)k * N + c];
            const float un = sSum[k] + suc - inter;
            m = fmaxf(m, inter / fmaxf(un, 1.0f));
        }
    }
    for (int off = 32; off > 0; off >>= 1) m = fmaxf(m, __shfl_down(m, off));
    __shared__ float lm[4];
    const int wave = tid >> 6, lane = tid & 63;
    if (lane == 0) lm[wave] = m;
    __syncthreads();
    if (tid == 0) comp[c] = fmaxf(fmaxf(lm[0], lm[1]), fmaxf(lm[2], lm[3]));
}

// ---------------------------------------------------------------------------
// K5: out[j] = sScore[j] * exp(-sigma * max_i(d_ij^2 - comp[i]^2)),
// d_ij = (i<j && label match) ? iou(i,j) : 0.
// ---------------------------------------------------------------------------
__global__ __launch_bounds__(256) void k_final(
    const unsigned* __restrict__ interBuf, const float* __restrict__ comp,
    const float* __restrict__ sSum, const int* __restrict__ sLabel,
    const float* __restrict__ sScore, float* __restrict__ out, int N)
{
    const int j = blockIdx.x;
    const int tid = threadIdx.x;
    const float suj = sSum[j];
    const int lj = sLabel[j];
    float m = -3.0e38f;
    for (int i = tid; i < N; i += 256) {
        const float ci = comp[i];
        float d = 0.0f;
        if (i < j && sLabel[i] == lj) {
            const float inter = (float)interBuf[(size_t)i * N + j];
            const float un = sSum[i] + suj - inter;
            d = inter / fmaxf(un, 1.0f);
        }
        m = fmaxf(m, d * d - ci * ci);
    }
    for (int off = 32; off > 0; off >>= 1) m = fmaxf(m, __shfl_down(m, off));
    __shared__ float lm[4];
    const int wave = tid >> 6, lane = tid & 63;
    if (lane == 0) lm[wave] = m;
    __syncthreads();
    if (tid == 0) {
        const float mm = fmaxf(fmaxf(lm[0], lm[1]), fmaxf(lm[2], lm[3]));
        out[j] = sScore[j] * expf(-SIGMA * mm);
    }
}

extern "C" void kernel_launch(void* const* d_in, const int* in_sizes, int n_in,
                              void* d_out, int out_size, void* d_ws, size_t ws_size,
                              hipStream_t stream)
{
    const float* preds  = (const float*)d_in[0];
    const float* cate   = (const float*)d_in[1];
    const int*   labels = (const int*)d_in[2];
    float* out = (float*)d_out;

    const int N = in_sizes[1];
    const int HW = in_sizes[0] / N;
    const int WORDS = HW >> 6;

    char* ws = (char*)d_ws;
    size_t off = 0;
    auto take = [&](size_t bytes) -> void* {
        void* p = ws + off;
        off = (off + bytes + 255) & ~(size_t)255;
        return p;
    };
    u64*      packed   = (u64*)     take((size_t)N * WORDS * sizeof(u64));  // ~4.1 MB
    double*   pssum    = (double*)  take((size_t)N * 4 * sizeof(double));
    int*      pcnt     = (int*)     take((size_t)N * 4 * sizeof(int));
    float*    sScore   = (float*)   take((size_t)N * sizeof(float));
    float*    sSum     = (float*)   take((size_t)N * sizeof(float));
    int*      sLabel   = (int*)     take((size_t)N * sizeof(int));
    int*      order    = (int*)     take((size_t)N * sizeof(int));
    float*    comp     = (float*)   take((size_t)N * sizeof(float));
    unsigned* interBuf = (unsigned*)take((size_t)N * N * sizeof(unsigned)); // ~1 MB
    (void)ws_size; (void)n_in; (void)out_size;

    // zero the atomic accumulator (ws arrives poisoned 0xAA)
    hipMemsetAsync(interBuf, 0, (size_t)N * N * sizeof(unsigned), stream);

    k_pack_score<<<N * 4, 256, 0, stream>>>(preds, packed, pssum, pcnt, HW);

    k_sort<<<1, 512, 0, stream>>>(pssum, pcnt, cate, labels,
                                  sScore, sSum, sLabel, order, N);

    const int NT = (N + TPB - 1) / TPB;
    dim3 grid(NT * (NT + 1) / 2, NSPLIT);
    k_inter<<<grid, 256, 0, stream>>>(packed, order, interBuf, N, WORDS, NT);

    k_comp<<<N, 256, 0, stream>>>(interBuf, sSum, sLabel, comp, N);

    k_final<<<N, 256, 0, stream>>>(interBuf, comp, sSum, sLabel, sScore, out, N);
}